// Round 9
// baseline (530.594 us; speedup 1.0000x reference)
//
#include <hip/hip_runtime.h>

#define DEVFN __device__ __forceinline__

namespace {

constexpr int NN = 50000;   // nodes
constexpr int NE = 600000;  // edges
constexpr int H  = 128;
constexpr float LN_EPS = 1e-6f;

typedef _Float16 f16x8 __attribute__((ext_vector_type(8)));
typedef _Float16 f16x4 __attribute__((ext_vector_type(4)));
typedef float f32x4 __attribute__((ext_vector_type(4)));

// acc[8][4] += xs_tile(8 rows x K) @ W(K x 128) restricted to cols c0..c0+3.
// (only used by the tiny one-time fold kernels now)
DEVFN void mm_block(const float* xsrow, int pitch, int K,
                    const float* __restrict__ W, int c0, float (&acc)[8][4]) {
  for (int k = 0; k < K; k += 4) {
    float4 w0 = *(const float4*)(W + (size_t)(k + 0) * H + c0);
    float4 w1 = *(const float4*)(W + (size_t)(k + 1) * H + c0);
    float4 w2 = *(const float4*)(W + (size_t)(k + 2) * H + c0);
    float4 w3 = *(const float4*)(W + (size_t)(k + 3) * H + c0);
#pragma unroll
    for (int r = 0; r < 8; ++r) {
      float4 a = *(const float4*)(xsrow + r * pitch + k);
      acc[r][0] += a.x * w0.x; acc[r][0] += a.y * w1.x; acc[r][0] += a.z * w2.x; acc[r][0] += a.w * w3.x;
      acc[r][1] += a.x * w0.y; acc[r][1] += a.y * w1.y; acc[r][1] += a.z * w2.y; acc[r][1] += a.w * w3.y;
      acc[r][2] += a.x * w0.z; acc[r][2] += a.y * w1.z; acc[r][2] += a.z * w2.z; acc[r][2] += a.w * w3.z;
      acc[r][3] += a.x * w0.w; acc[r][3] += a.y * w1.w; acc[r][3] += a.z * w2.w; acc[r][3] += a.w * w3.w;
    }
  }
}

// shared fp32 linear body: y[r0..r0+32) = x @ W  (K=128, N=128)
DEVFN void linear_body(const float* __restrict__ x, const float* __restrict__ W,
                       float* __restrict__ y, int r0, int R, int t, float* xs) {
  {
    const int r = t & 31, q = t >> 5;
    int row = r0 + r;
    if (row >= R) row = R - 1;
    const float* src = &x[(size_t)row * H + q * 32];
#pragma unroll
    for (int j = 0; j < 8; ++j)
      *(float4*)&xs[r * 132 + q * 32 + j * 4] = *(const float4*)&src[j * 4];
  }
  __syncthreads();
  const int c0 = (t & 31) * 4;
  const int rbase = (t >> 5) * 8;
  float acc[8][4];
#pragma unroll
  for (int r = 0; r < 8; ++r) { acc[r][0] = 0.f; acc[r][1] = 0.f; acc[r][2] = 0.f; acc[r][3] = 0.f; }
  mm_block(&xs[rbase * 132], 132, H, W, c0, acc);
#pragma unroll
  for (int r = 0; r < 8; ++r) {
    int row = r0 + rbase + r;
    if (row < R)
      *(float4*)&y[(size_t)row * H + c0] =
          make_float4(acc[r][0], acc[r][1], acc[r][2], acc[r][3]);
  }
}

// ---------------- fold stage 1: T = Wb@W0b (blocks 0-3), Wf = Wt@W0b (blocks 4-7) ----------------
__global__ __launch_bounds__(128) void fold1_kernel(
    const float* __restrict__ Wb, const float* __restrict__ Wt,
    const float* __restrict__ W0b, float* __restrict__ T,
    float* __restrict__ Wf) {
  __shared__ float xs[32 * 132];
  const float* x = (blockIdx.x < 4) ? Wb : Wt;
  float* y = (blockIdx.x < 4) ? T : Wf;
  linear_body(x, W0b, y, (blockIdx.x & 3) * 32, 128, threadIdx.x, xs);
}

// ---------------- fold stage 2: Wc2 = W1e@T (blocks 0-3), bc2 = b1e@T (block 4) ----------------
__global__ __launch_bounds__(128) void fold2_kernel(
    const float* __restrict__ W1e, const float* __restrict__ b1e,
    const float* __restrict__ T, float* __restrict__ Wc2,
    float* __restrict__ bc2) {
  __shared__ float xs[32 * 132];
  if (blockIdx.x < 4) {
    linear_body(W1e, T, Wc2, blockIdx.x * 32, 128, threadIdx.x, xs);
  } else {
    int j = threadIdx.x;
    float s = 0.f;
    for (int k = 0; k < H; ++k) s += b1e[k] * T[(size_t)k * H + j];
    bc2[j] = s;
  }
}

// ---------------- prepack 7 weight matrices -> MFMA B-fragment order, fp16 ----------------
__global__ __launch_bounds__(64) void prepack7_kernel(
    const float* __restrict__ s0, const float* __restrict__ s1,
    const float* __restrict__ s2, const float* __restrict__ s3,
    const float* __restrict__ s4, const float* __restrict__ s5,
    const float* __restrict__ s6, _Float16* __restrict__ pkBase) {
  const int z = blockIdx.z;
  const float* W = (z == 0) ? s0 : (z == 1) ? s1 : (z == 2) ? s2 :
                   (z == 3) ? s3 : (z == 4) ? s4 : (z == 5) ? s5 : s6;
  _Float16* pk = pkBase + (size_t)z * 128 * H;
  const int ks = blockIdx.x, ct = blockIdx.y, l = threadIdx.x;
  const int kbase = ks * 32 + (l >> 4) * 8;
  const int col = ct * 16 + (l & 15);
  _Float16 tmp[8];
#pragma unroll
  for (int j = 0; j < 8; ++j)
    tmp[j] = (_Float16)W[(size_t)(kbase + j) * H + col];
  *(f16x8*)&pk[((size_t)((ks * 8 + ct) * 64) + l) * 8] = *(f16x8*)tmp;
}

// ---- prepack W0e[16 x 128] -> MFMA B-fragment (K padded 16->32; row 16 = bias b0e) ----
__global__ __launch_bounds__(64) void prepack_w0e_kernel(
    const float* __restrict__ W0e, const float* __restrict__ b0e,
    _Float16* __restrict__ pk) {
  const int ct = blockIdx.x, l = threadIdx.x;
  const int quad = l >> 4;
  const int col = ct * 16 + (l & 15);
  _Float16 tmp[8];
#pragma unroll
  for (int j = 0; j < 8; ++j) {
    int k = quad * 8 + j;
    float v = (quad < 2) ? W0e[(size_t)k * H + col] : (k == 16 ? b0e[col] : 0.f);
    tmp[j] = (_Float16)v;
  }
  *(f16x8*)&pk[((size_t)(ct * 64) + l) * 8] = *(f16x8*)tmp;
}

// ---------------- prepack W[32 x 128] -> MFMA B-fragment (single K=32 step) ----------
__global__ __launch_bounds__(64) void prepack_k32_kernel(
    const float* __restrict__ W, _Float16* __restrict__ pk) {
  const int ct = blockIdx.x, l = threadIdx.x;
  const int quad = l >> 4;
  const int col = ct * 16 + (l & 15);
  _Float16 tmp[8];
#pragma unroll
  for (int j = 0; j < 8; ++j)
    tmp[j] = (_Float16)W[(size_t)(quad * 8 + j) * H + col];
  *(f16x8*)&pk[((size_t)(ct * 64) + l) * 8] = *(f16x8*)tmp;
}

// ---------------- counting sort by receiver ----------------
__global__ __launch_bounds__(256) void hist_kernel(const int* __restrict__ recv,
                                                   int* __restrict__ cnt) {
  int i = blockIdx.x * 256 + threadIdx.x;
  if (i < NE) atomicAdd(&cnt[recv[i]], 1);
}

__global__ __launch_bounds__(256) void scan1_kernel(const int* __restrict__ cnt,
                                                    int* __restrict__ excl,
                                                    int* __restrict__ part) {
  __shared__ int s[256];
  int t = threadIdx.x;
  int i = blockIdx.x * 256 + t;
  int v = (i < NN) ? cnt[i] : 0;
  s[t] = v;
  __syncthreads();
  for (int off = 1; off < 256; off <<= 1) {
    int x = (t >= off) ? s[t - off] : 0;
    __syncthreads();
    s[t] += x;
    __syncthreads();
  }
  if (i < NN) excl[i] = s[t] - v;
  if (t == 255) part[blockIdx.x] = s[255];
}

__global__ __launch_bounds__(256) void scan2_kernel(int* __restrict__ part, int nb) {
  __shared__ int s[256];
  int t = threadIdx.x;
  int v = (t < nb) ? part[t] : 0;
  s[t] = v;
  __syncthreads();
  for (int off = 1; off < 256; off <<= 1) {
    int x = (t >= off) ? s[t - off] : 0;
    __syncthreads();
    s[t] += x;
    __syncthreads();
  }
  if (t < nb) part[t] = s[t] - v;
}

__global__ __launch_bounds__(256) void scan3_kernel(int* __restrict__ excl,
                                                    const int* __restrict__ part,
                                                    int* __restrict__ cursor) {
  int i = blockIdx.x * 256 + threadIdx.x;
  if (i < NN) {
    int e = excl[i] + part[i >> 8];
    excl[i] = e;
    cursor[i] = e;
  }
}

// ---------------- scatter + edge-row permute (fp16) in ONE pass ----------------
__global__ __launch_bounds__(256) void scatter_permute_kernel(
    const int* __restrict__ senders, const int* __restrict__ recv,
    int* __restrict__ cursor, const float* __restrict__ edges,
    int* __restrict__ sendp, _Float16* __restrict__ edgesP16) {
  const int t = threadIdx.x;
  const int i = blockIdx.x * 64 + (t >> 2);
  if (i >= NE) return;
  const int sub = t & 3;
  int pos = 0;
  if (sub == 0) pos = atomicAdd(&cursor[recv[i]], 1);
  pos = __shfl(pos, (t & 63) & ~3);
  if (sub == 0) sendp[pos] = senders[i];
  float4 v = *(const float4*)&edges[(size_t)i * 16 + sub * 4];
  f16x4 h = {(_Float16)v.x, (_Float16)v.y, (_Float16)v.z, (_Float16)v.w};
  *(f16x4*)&edgesP16[(size_t)pos * 16 + sub * 4] = h;
}

// ---------------- MFMA encoder: n16 = relu(x@W0+b0)@W1+b1  (x is [NN,32] fp32) ----
__global__ __launch_bounds__(256) void encoder_mfma_kernel(
    const float* __restrict__ x, const float* __restrict__ b0,
    const float* __restrict__ b1, const _Float16* __restrict__ pkEW0,
    const _Float16* __restrict__ pkEW1, _Float16* __restrict__ outp) {
  __shared__ _Float16 lds[4][16 * 136];
  const int t = threadIdx.x;
  const int wave = t >> 6, lane = t & 63;
  const int row0 = blockIdx.x * 64 + wave * 16;
  const int quad = lane >> 4, m16 = lane & 15;
  _Float16* hlds = &lds[wave][0];

  int arow = row0 + m16;
  if (arow >= NN) arow = NN - 1;
  f16x8 a0;
  {
    const float* src = &x[(size_t)arow * 32 + quad * 8];
    float4 v0 = *(const float4*)(src);
    float4 v1 = *(const float4*)(src + 4);
    a0[0] = (_Float16)v0.x; a0[1] = (_Float16)v0.y;
    a0[2] = (_Float16)v0.z; a0[3] = (_Float16)v0.w;
    a0[4] = (_Float16)v1.x; a0[5] = (_Float16)v1.y;
    a0[6] = (_Float16)v1.z; a0[7] = (_Float16)v1.w;
  }
#pragma unroll
  for (int ct = 0; ct < 8; ++ct) {
    float bb = b0[ct * 16 + m16];
    f32x4 acc = (f32x4){bb, bb, bb, bb};
    acc = __builtin_amdgcn_mfma_f32_16x16x32_f16(
        a0, *(const f16x8*)&pkEW0[((size_t)(ct * 64) + lane) * 8], acc, 0, 0, 0);
#pragma unroll
    for (int q = 0; q < 4; ++q)
      hlds[(quad * 4 + q) * 136 + ct * 16 + m16] = (_Float16)fmaxf(acc[q], 0.f);
  }
  __syncthreads();
  const _Float16* hrow = &hlds[m16 * 136 + quad * 8];
  f16x8 ah[4];
#pragma unroll
  for (int ks = 0; ks < 4; ++ks) ah[ks] = *(const f16x8*)(hrow + ks * 32);
  f32x4 acc2[8];
#pragma unroll
  for (int ct = 0; ct < 8; ++ct) {
    float bb = b1[ct * 16 + m16];
    acc2[ct] = (f32x4){bb, bb, bb, bb};
  }
#pragma unroll
  for (int ks = 0; ks < 4; ++ks) {
    const _Float16* bp = pkEW1 + ((size_t)ks * 8 * 64 + lane) * 8;
#pragma unroll
    for (int ct = 0; ct < 8; ++ct)
      acc2[ct] = __builtin_amdgcn_mfma_f32_16x16x32_f16(
          ah[ks], *(const f16x8*)(bp + ct * 512), acc2[ct], 0, 0, 0);
  }
  __syncthreads();  // ah reads done before overwrite
#pragma unroll
  for (int ct = 0; ct < 8; ++ct)
#pragma unroll
    for (int q = 0; q < 4; ++q)
      hlds[(quad * 4 + q) * 136 + ct * 16 + m16] = (_Float16)acc2[ct][q];
  __syncthreads();
  {
    int lr = lane >> 2, cc = (lane & 3) * 32;
    int orow = row0 + lr;
    if (orow < NN) {
      const _Float16* src = &hlds[lr * 136 + cc];
      _Float16* dst = &outp[(size_t)orow * H + cc];
      *(f16x8*)(dst + 0)  = *(const f16x8*)(src + 0);
      *(f16x8*)(dst + 8)  = *(const f16x8*)(src + 8);
      *(f16x8*)(dst + 16) = *(const f16x8*)(src + 16);
      *(f16x8*)(dst + 24) = *(const f16x8*)(src + 24);
    }
  }
}

// ---------------- fused Hs + blin: B2pk = pack_C( Hs @ Wc2 + deg*bc2 + b0n ) ----------
// Block = one 16-node tile, 256 threads = 4 waves. Stage 1: wave w owns nodes
// tile*16 + w*4 + 0..3 — first edge-tile of all 4 nodes is PIPELINED, deg>16
// tails in a short residual loop. Bias folded into pkW0e row 16 via a
// constant-1 A column. Stage 2: one barrier, 4 waves x 2 ct-blocks of
// B2 = Hl@Wc2 + deg*bc2 + b0n (node_b0 folded here so node_mfma skips it).
__global__ __launch_bounds__(256) void hsblin_kernel(
    const _Float16* __restrict__ edgesP16, const int* __restrict__ start,
    const int* __restrict__ endc, const _Float16* __restrict__ pkW0e,
    const _Float16* __restrict__ pkWc2, const float* __restrict__ bc2,
    const float* __restrict__ b0n, _Float16* __restrict__ B2pk) {
  __shared__ _Float16 hl[16][136];
  __shared__ float degl[16];
  const int t = threadIdx.x;
  const int wave = t >> 6, lane = t & 63;
  const int quad = lane >> 4, m16 = lane & 15;
  const int tile = blockIdx.x;
  const int vb = tile * 16 + wave * 4;

  f16x8 bfrag[8];
#pragma unroll
  for (int ct = 0; ct < 8; ++ct)
    bfrag[ct] = *(const f16x8*)&pkW0e[((size_t)(ct * 64) + lane) * 8];

  int j0[4], dg[4];
#pragma unroll
  for (int k = 0; k < 4; ++k) j0[k] = start[vb + k];
#pragma unroll
  for (int k = 0; k < 4; ++k) dg[k] = endc[vb + k] - j0[k];

  float rs[4][8];
#pragma unroll
  for (int k = 0; k < 4; ++k)
#pragma unroll
    for (int ct = 0; ct < 8; ++ct) rs[k][ct] = 0.f;

  // ---- first edge-tile of all 4 nodes: loads issued back-to-back (ILP) ----
  f16x8 a0[4];
#pragma unroll
  for (int k = 0; k < 4; ++k) {
    const bool valid = (m16 < dg[k]);
    f16x8 a = {};
    if (quad < 2) {
      if (valid)
        a = *(const f16x8*)&edgesP16[(size_t)(j0[k] + m16) * 16 + quad * 8];
    } else if (quad == 2) {
      a[0] = valid ? (_Float16)1.f : (_Float16)0.f;
    }
    a0[k] = a;
  }
#pragma unroll
  for (int k = 0; k < 4; ++k) {
#pragma unroll
    for (int ct = 0; ct < 8; ++ct) {
      f32x4 acc = (f32x4){0.f, 0.f, 0.f, 0.f};
      acc = __builtin_amdgcn_mfma_f32_16x16x32_f16(a0[k], bfrag[ct], acc, 0, 0, 0);
      rs[k][ct] += (fmaxf(acc[0], 0.f) + fmaxf(acc[1], 0.f)) +
                   (fmaxf(acc[2], 0.f) + fmaxf(acc[3], 0.f));
    }
  }
  // ---- residual tiles for deg > 16 (rare) ----
#pragma unroll
  for (int k = 0; k < 4; ++k) {
    for (int base = 16; base < dg[k]; base += 16) {
      const bool valid = (base + m16 < dg[k]);
      f16x8 a = {};
      if (quad < 2) {
        if (valid)
          a = *(const f16x8*)&edgesP16[(size_t)(j0[k] + base + m16) * 16 + quad * 8];
      } else if (quad == 2) {
        a[0] = valid ? (_Float16)1.f : (_Float16)0.f;
      }
#pragma unroll
      for (int ct = 0; ct < 8; ++ct) {
        f32x4 acc = (f32x4){0.f, 0.f, 0.f, 0.f};
        acc = __builtin_amdgcn_mfma_f32_16x16x32_f16(a, bfrag[ct], acc, 0, 0, 0);
        rs[k][ct] += (fmaxf(acc[0], 0.f) + fmaxf(acc[1], 0.f)) +
                     (fmaxf(acc[2], 0.f) + fmaxf(acc[3], 0.f));
      }
    }
  }
  // ---- reduce 16 tile-rows per node; lanes 0..15 write the Hs row to LDS ----
#pragma unroll
  for (int k = 0; k < 4; ++k) {
#pragma unroll
    for (int ct = 0; ct < 8; ++ct) {
      float s = rs[k][ct];
      s += __shfl_xor(s, 16);
      s += __shfl_xor(s, 32);
      rs[k][ct] = s;
    }
    const int nl = wave * 4 + k;
    if (lane < 16) {
#pragma unroll
      for (int ct = 0; ct < 8; ++ct)
        hl[nl][ct * 16 + lane] = (_Float16)rs[k][ct];
    }
    if (lane == 16) degl[nl] = (float)dg[k];
  }
  __syncthreads();

  // ---- stage 2: wave handles ct = 2*wave, 2*wave+1 ----
  f16x8 ah[4];
#pragma unroll
  for (int ks = 0; ks < 4; ++ks)
    ah[ks] = *(const f16x8*)&hl[m16][ks * 32 + quad * 8];
  float degq[4];
#pragma unroll
  for (int q = 0; q < 4; ++q) degq[q] = degl[quad * 4 + q];
  f32x4 acc2[2];
#pragma unroll
  for (int i = 0; i < 2; ++i) {
    int ct = wave * 2 + i;
    float bcv = bc2[ct * 16 + m16];
    float b0v = b0n[ct * 16 + m16];
    acc2[i] = (f32x4){degq[0] * bcv + b0v, degq[1] * bcv + b0v,
                      degq[2] * bcv + b0v, degq[3] * bcv + b0v};
  }
#pragma unroll
  for (int ks = 0; ks < 4; ++ks) {
#pragma unroll
    for (int i = 0; i < 2; ++i) {
      int ct = wave * 2 + i;
      const _Float16* bp = pkWc2 + ((size_t)((ks * 8 + ct) * 64) + lane) * 8;
      acc2[i] = __builtin_amdgcn_mfma_f32_16x16x32_f16(
          ah[ks], *(const f16x8*)bp, acc2[i], 0, 0, 0);
    }
  }
  _Float16 tmp[8];
#pragma unroll
  for (int i = 0; i < 2; ++i)
#pragma unroll
    for (int q = 0; q < 4; ++q) tmp[i * 4 + q] = (_Float16)acc2[i][q];
  *(f16x8*)&B2pk[((size_t)tile * 64 + lane) * 32 + wave * 8] = *(f16x8*)tmp;
}

// ---------------- per-pass: S[v] = sum_{s in N(v)} n16[s]  (16-deep ILP) ----------
__global__ __launch_bounds__(256) void gather_kernel(
    const _Float16* __restrict__ n16, const int* __restrict__ start,
    const int* __restrict__ endc, const int* __restrict__ sendp,
    _Float16* __restrict__ S) {
  const int t = threadIdx.x;
  const int v = blockIdx.x * 4 + (t >> 6);  // NN % 4 == 0
  const int lane = t & 63;
  const int grp = lane >> 4;
  const int c = (lane & 15) * 8;
  float a[8] = {0.f, 0.f, 0.f, 0.f, 0.f, 0.f, 0.f, 0.f};
  const int e = endc[v];
  for (int j = start[v]; j < e; j += 16) {
    int js[4];
    float w[4];
#pragma unroll
    for (int i = 0; i < 4; ++i) {
      int jj = j + grp + i * 4;
      w[i] = (jj < e) ? 1.f : 0.f;
      js[i] = (jj < e) ? jj : (e - 1);
    }
    int sx[4];
#pragma unroll
    for (int i = 0; i < 4; ++i) sx[i] = sendp[js[i]];
    f16x8 p[4];
#pragma unroll
    for (int i = 0; i < 4; ++i)
      p[i] = *(const f16x8*)&n16[(size_t)sx[i] * H + c];
#pragma unroll
    for (int i = 0; i < 4; ++i)
#pragma unroll
      for (int k = 0; k < 8; ++k) a[k] = fmaf(w[i], (float)p[i][k], a[k]);
  }
#pragma unroll
  for (int i = 0; i < 8; ++i) {
    a[i] += __shfl_xor(a[i], 16);
    a[i] += __shfl_xor(a[i], 32);
  }
  if (lane < 16) {
    f16x8 o;
#pragma unroll
    for (int i = 0; i < 8; ++i) o[i] = (_Float16)a[i];
    *(f16x8*)&S[(size_t)v * H + c] = o;
  }
}

// ---------------- MFMA node update (v3: 16 rows/wave, barrier-free) ----------------
// pre-act = n@W0t + S@Wf + B2' ; h = relu(pre-act)   (B2' has b0 pre-folded)
// out = LN(h@W1 + n@Wn + b1)
// 16 rows per wave -> 3125 waves (12.2/CU) for max latency hiding; per-wave h
// LDS buffer -> zero __syncthreads.
__global__ __launch_bounds__(256) void node_mfma_kernel(
    const _Float16* __restrict__ n16, const _Float16* __restrict__ S16,
    const _Float16* __restrict__ B2pk,
    const _Float16* __restrict__ pkW0t, const _Float16* __restrict__ pkWf,
    const _Float16* __restrict__ pkW1, const _Float16* __restrict__ pkWn,
    const float* __restrict__ b1,
    const float* __restrict__ ln_g, const float* __restrict__ ln_b,
    _Float16* __restrict__ nout) {
  __shared__ _Float16 lds[4][16 * 136];
  const int t = threadIdx.x;
  const int wave = t >> 6, lane = t & 63;
  const int row0 = blockIdx.x * 64 + wave * 16;
  const int quad = lane >> 4, m16 = lane & 15;
  _Float16* hlds = &lds[wave][0];

  int arow = row0 + m16;
  if (arow >= NN) arow = NN - 1;
  const _Float16* nrow = &n16[(size_t)arow * H + quad * 8];
  const _Float16* srow = &S16[(size_t)arow * H + quad * 8];
  f16x8 an[4], as[4];
#pragma unroll
  for (int ks = 0; ks < 4; ++ks) {
    an[ks] = *(const f16x8*)(nrow + ks * 32);
    as[ks] = *(const f16x8*)(srow + ks * 32);
  }

  const int tile = blockIdx.x * 4 + wave;
  const _Float16* b2l = &B2pk[((size_t)tile * 64 + lane) * 32];
  f32x4 acc[8];
#pragma unroll
  for (int ct = 0; ct < 8; ++ct) {
    f16x4 bv = *(const f16x4*)(b2l + ct * 4);
    acc[ct] = (f32x4){(float)bv[0], (float)bv[1], (float)bv[2], (float)bv[3]};
  }
#pragma unroll
  for (int ks = 0; ks < 4; ++ks) {
    const _Float16* bp0 = pkW0t + ((size_t)ks * 8 * 64 + lane) * 8;
    const _Float16* bpf = pkWf + ((size_t)ks * 8 * 64 + lane) * 8;
#pragma unroll
    for (int ct = 0; ct < 8; ++ct) {
      f16x8 bw0 = *(const f16x8*)(bp0 + ct * 512);
      acc[ct] = __builtin_amdgcn_mfma_f32_16x16x32_f16(an[ks], bw0, acc[ct], 0, 0, 0);
      f16x8 bwf = *(const f16x8*)(bpf + ct * 512);
      acc[ct] = __builtin_amdgcn_mfma_f32_16x16x32_f16(as[ks], bwf, acc[ct], 0, 0, 0);
    }
  }
  // relu -> per-wave LDS (same-wave RAW; compiler orders via lgkmcnt)
#pragma unroll
  for (int ct = 0; ct < 8; ++ct) {
#pragma unroll
    for (int q = 0; q < 4; ++q)
      hlds[(quad * 4 + q) * 136 + ct * 16 + m16] =
          (_Float16)fmaxf(acc[ct][q], 0.f);
  }

  const _Float16* hrow = &hlds[m16 * 136 + quad * 8];
  f32x4 acc2[8];
#pragma unroll
  for (int ct = 0; ct < 8; ++ct) {
    float bb = b1[ct * 16 + m16];
    acc2[ct] = (f32x4){bb, bb, bb, bb};
  }
#pragma unroll
  for (int ks = 0; ks < 4; ++ks) {
    f16x8 ah = *(const f16x8*)(hrow + ks * 32);
    const _Float16* bp1 = pkW1 + ((size_t)ks * 8 * 64 + lane) * 8;
    const _Float16* bpn = pkWn + ((size_t)ks * 8 * 64 + lane) * 8;
#pragma unroll
    for (int ct = 0; ct < 8; ++ct) {
      f16x8 b1f = *(const f16x8*)(bp1 + ct * 512);
      acc2[ct] = __builtin_amdgcn_mfma_f32_16x16x32_f16(ah, b1f, acc2[ct], 0, 0, 0);
      f16x8 bnf = *(const f16x8*)(bpn + ct * 512);
      acc2[ct] = __builtin_amdgcn_mfma_f32_16x16x32_f16(an[ks], bnf, acc2[ct], 0, 0, 0);
    }
  }

  float gv[8], bv[8];
#pragma unroll
  for (int ct = 0; ct < 8; ++ct) {
    gv[ct] = ln_g[ct * 16 + m16];
    bv[ct] = ln_b[ct * 16 + m16];
  }
  // ---- LayerNorm + store (per-wave; in-wave shfl; no barriers) ----
#pragma unroll
  for (int q = 0; q < 4; ++q) {
    float s1 = 0.f, s2 = 0.f;
#pragma unroll
    for (int ct = 0; ct < 8; ++ct) {
      float v = acc2[ct][q];
      s1 += v; s2 += v * v;
    }
#pragma unroll
    for (int m = 1; m <= 8; m <<= 1) {
      s1 += __shfl_xor(s1, m);
      s2 += __shfl_xor(s2, m);
    }
    float mu = s1 * (1.f / 128.f);
    float var = s2 * (1.f / 128.f) - mu * mu;
    float rs = rsqrtf(var + LN_EPS);
#pragma unroll
    for (int ct = 0; ct < 8; ++ct) {
      float o = (acc2[ct][q] - mu) * rs * gv[ct] + bv[ct];
      hlds[(quad * 4 + q) * 136 + ct * 16 + m16] = (_Float16)o;
    }
  }
  {
    int lr = lane >> 2;
    int cc = (lane & 3) * 32;
    const _Float16* src = &hlds[lr * 136 + cc];
    int orow = row0 + lr;
    if (orow < NN) {
      _Float16* dst = &nout[(size_t)orow * H + cc];
      *(f16x8*)(dst + 0)  = *(const f16x8*)(src + 0);
      *(f16x8*)(dst + 8)  = *(const f16x8*)(src + 8);
      *(f16x8*)(dst + 16) = *(const f16x8*)(src + 16);
      *(f16x8*)(dst + 24) = *(const f16x8*)(src + 24);
    }
  }
}

// ---------------- MFMA decoder: out = relu(n@W0+b0)@W1 + b1  (layer2 fp32) ----------
__global__ __launch_bounds__(256) void decode_mfma_kernel(
    const _Float16* __restrict__ n, const float* __restrict__ b0,
    const _Float16* __restrict__ pkDW0, const float* __restrict__ W1,
    const float* __restrict__ b1, float* __restrict__ out) {
  const int t = threadIdx.x;
  const int wave = t >> 6, lane = t & 63;
  const int row0 = blockIdx.x * 64 + wave * 16;
  const int quad = lane >> 4, m16 = lane & 15;
  int arow = row0 + m16;
  if (arow >= NN) arow = NN - 1;
  const _Float16* nrow = &n[(size_t)arow * H + quad * 8];
  f16x8 an[4];
#pragma unroll
  for (int ks = 0; ks < 4; ++ks) an[ks] = *(const f16x8*)(nrow + ks * 32);
  f32x4 acc[8];
#pragma unroll
  for (int ct = 0; ct < 8; ++ct) {
    float bb = b0[ct * 16 + m16];
    acc[ct] = (f32x4){bb, bb, bb, bb};
  }
#pragma unroll
  for (int ks = 0; ks < 4; ++ks) {
    const _Float16* bp = pkDW0 + ((size_t)ks * 8 * 64 + lane) * 8;
#pragma unroll
    for (int ct = 0; ct < 8; ++ct)
      acc[ct] = __builtin_amdgcn_mfma_f32_16x16x32_f16(
          an[ks], *(const f16x8*)(bp + ct * 512), acc[ct], 0, 0, 0);
  }
  float s0[4] = {0.f, 0.f, 0.f, 0.f}, s1[4] = {0.f, 0.f, 0.f, 0.f};
#pragma unroll
  for (int ct = 0; ct < 8; ++ct) {
    const float2 w = *(const float2*)&W1[(size_t)(ct * 16 + m16) * 2];
#pragma unroll
    for (int q = 0; q < 4; ++q) {
      float h = fmaxf(acc[ct][q], 0.f);
      s0[q] += h * w.x;
      s1[q] += h * w.y;
    }
  }
#pragma unroll
  for (int q = 0; q < 4; ++q) {
#pragma unroll
    for (int m = 1; m <= 8; m <<= 1) {
      s0[q] += __shfl_xor(s0[q], m);
      s1[q] += __shfl_xor(s1[q], m);
    }
  }
  if (m16 == 0) {
#pragma unroll
    for (int q = 0; q < 4; ++q) {
      int r = row0 + quad * 4 + q;
      if (r < NN) {
        out[(size_t)r * 2 + 0] = s0[q] + b1[0];
        out[(size_t)r * 2 + 1] = s1[q] + b1[1];
      }
    }
  }
}

__global__ __launch_bounds__(256) void zero_kernel(float4* __restrict__ p, int n4) {
  int i = blockIdx.x * 256 + threadIdx.x;
  if (i < n4) p[i] = make_float4(0.f, 0.f, 0.f, 0.f);
}

}  // namespace

extern "C" void kernel_launch(void* const* d_in, const int* in_sizes, int n_in,
                              void* d_out, int out_size, void* d_ws, size_t ws_size,
                              hipStream_t stream) {
  const float* nodes     = (const float*)d_in[0];
  const float* edges     = (const float*)d_in[1];
  const int*   senders   = (const int*)d_in[2];
  const int*   receivers = (const int*)d_in[3];
  const float* enc_n_W0 = (const float*)d_in[4];
  const float* enc_n_b0 = (const float*)d_in[5];
  const float* enc_n_W1 = (const float*)d_in[6];
  const float* enc_n_b1 = (const float*)d_in[7];
  const float* enc_e_W0 = (const float*)d_in[8];
  const float* enc_e_b0 = (const float*)d_in[9];
  const float* enc_e_W1 = (const float*)d_in[10];
  const float* enc_e_b1 = (const float*)d_in[11];
  const float* W_msg    = (const float*)d_in[12];
  const float* node_W0  = (const float*)d_in[13];
  const float* node_b0  = (const float*)d_in[14];
  const float* node_W1  = (const float*)d_in[15];
  const float* node_b1  = (const float*)d_in[16];
  const float* W_node   = (const float*)d_in[17];
  const float* ln_g     = (const float*)d_in[18];
  const float* ln_b     = (const float*)d_in[19];
  const float* dec_W0   = (const float*)d_in[20];
  const float* dec_b0   = (const float*)d_in[21];
  const float* dec_W1   = (const float*)d_in[22];
  const float* dec_b1   = (const float*)d_in[23];
  float* out = (float*)d_out;

  const float* Wt  = W_msg;                // rows 0..127 of W_msg
  const float* Wb  = W_msg + 128 * H;      // rows 128..255
  const float* W0t = node_W0;              // rows 0..127 of node_W0
  const float* W0b = node_W0 + 128 * H;    // rows 128..255

  const int mfmaBlocks = (NN + 63) / 64;   // 782 (encoder/decoder/node)
  const int nTiles     = mfmaBlocks * 4;   // 3128
  const int hsTiles    = NN / 16;          // 3125 (exact)

  // workspace layout
  float* T      = (float*)d_ws;                        // 128*128 f32
  float* Wc2    = T + 128 * H;
  float* Wf32   = Wc2 + 128 * H;
  float* bc2    = Wf32 + 128 * H;                      // 128
  _Float16* edgesP16 = (_Float16*)(bc2 + 128);         // NE*16 f16 (19.2 MB)
  _Float16* n16a  = edgesP16 + (size_t)NE * 16;        // NN*H f16
  _Float16* n16b  = n16a + (size_t)NN * H;
  _Float16* S16   = n16b + (size_t)NN * H;
  _Float16* B2pk  = S16 + (size_t)NN * H;              // nTiles*64*32 f16
  _Float16* pkAll = B2pk + (size_t)nTiles * 64 * 32;   // 7 x 128*H f16 contiguous
  _Float16* pkW0t = pkAll;
  _Float16* pkWf  = pkAll + 1 * 128 * H;
  _Float16* pkW1  = pkAll + 2 * 128 * H;
  _Float16* pkWn  = pkAll + 3 * 128 * H;
  _Float16* pkEW1 = pkAll + 4 * 128 * H;
  _Float16* pkDW0 = pkAll + 5 * 128 * H;
  _Float16* pkWc2 = pkAll + 6 * 128 * H;
  _Float16* pkW0e = pkAll + 7 * 128 * H;               // 8*64*8 = 4096 f16
  _Float16* pkEW0 = pkW0e + 4096;                      // 4096 f16
  int* cnt    = (int*)(pkEW0 + 4096);
  int* excl   = cnt + NN;
  int* cursor = excl + NN;
  int* part   = cursor + NN;               // 256
  int* sendp  = part + 256;                // NE

  const int scanBlocks = (NN + 255) / 256;   // 196
  const int neBlocks   = (NE + 255) / 256;   // 2344

  // --- one-time: sort edges by receiver (scatter fused with fp16 row permute) ---
  zero_kernel<<<(NN / 4 + 255) / 256, 256, 0, stream>>>((float4*)cnt, NN / 4);
  hist_kernel<<<neBlocks, 256, 0, stream>>>(receivers, cnt);
  scan1_kernel<<<scanBlocks, 256, 0, stream>>>(cnt, excl, part);
  scan2_kernel<<<1, 256, 0, stream>>>(part, scanBlocks);
  scan3_kernel<<<scanBlocks, 256, 0, stream>>>(excl, part, cursor);
  scatter_permute_kernel<<<(NE + 63) / 64, 256, 0, stream>>>(
      senders, receivers, cursor, edges, sendp, edgesP16);

  // --- fold chains:  T = Wb@W0b; Wf = Wt@W0b;  then Wc2 = W1e@T, bc2 = b1e@T ---
  fold1_kernel<<<8, 128, 0, stream>>>(Wb, Wt, W0b, T, Wf32);
  fold2_kernel<<<5, 128, 0, stream>>>(enc_e_W1, enc_e_b1, T, Wc2, bc2);
  prepack7_kernel<<<dim3(4, 8, 7), 64, 0, stream>>>(
      W0t, Wf32, node_W1, W_node, enc_n_W1, dec_W0, Wc2, pkAll);
  prepack_w0e_kernel<<<8, 64, 0, stream>>>(enc_e_W0, enc_e_b0, pkW0e);
  prepack_k32_kernel<<<8, 64, 0, stream>>>(enc_n_W0, pkEW0);

  encoder_mfma_kernel<<<mfmaBlocks, 256, 0, stream>>>(
      nodes, enc_n_b0, enc_n_b1, pkEW0, pkEW1, n16a);
  // zero the 3 tail tiles of B2pk (read by node_mfma's dead rows; NaN-proofing)
  zero_kernel<<<3, 256, 0, stream>>>(
      (float4*)(B2pk + (size_t)hsTiles * 64 * 32), (nTiles - hsTiles) * 512);
  hsblin_kernel<<<hsTiles, 256, 0, stream>>>(
      edgesP16, excl, cursor, pkW0e, pkWc2, bc2, node_b0, B2pk);

  // --- 5 weight-tied passes ---
  _Float16* ncur = n16a;
  _Float16* nnxt = n16b;
  for (int p = 0; p < 5; ++p) {
    gather_kernel<<<NN / 4, 256, 0, stream>>>(ncur, excl, cursor, sendp, S16);
    node_mfma_kernel<<<mfmaBlocks, 256, 0, stream>>>(
        ncur, S16, B2pk, pkW0t, pkWf, pkW1, pkWn, node_b1,
        ln_g, ln_b, nnxt);
    _Float16* tmp = ncur; ncur = nnxt; nnxt = tmp;
  }

  decode_mfma_kernel<<<mfmaBlocks, 256, 0, stream>>>(
      ncur, dec_b0, pkDW0, dec_W1, dec_b1, out);
}

// Round 10
// 513.527 us; speedup vs baseline: 1.0332x; 1.0332x over previous
//
#include <hip/hip_runtime.h>

#define DEVFN __device__ __forceinline__

namespace {

constexpr int NN = 50000;   // nodes
constexpr int NE = 600000;  // edges
constexpr int H  = 128;
constexpr float LN_EPS = 1e-6f;

typedef _Float16 f16x8 __attribute__((ext_vector_type(8)));
typedef _Float16 f16x4 __attribute__((ext_vector_type(4)));
typedef float f32x4 __attribute__((ext_vector_type(4)));

// acc[8][4] += xs_tile(8 rows x K) @ W(K x 128) restricted to cols c0..c0+3.
// (only used by the tiny one-time fold kernels now)
DEVFN void mm_block(const float* xsrow, int pitch, int K,
                    const float* __restrict__ W, int c0, float (&acc)[8][4]) {
  for (int k = 0; k < K; k += 4) {
    float4 w0 = *(const float4*)(W + (size_t)(k + 0) * H + c0);
    float4 w1 = *(const float4*)(W + (size_t)(k + 1) * H + c0);
    float4 w2 = *(const float4*)(W + (size_t)(k + 2) * H + c0);
    float4 w3 = *(const float4*)(W + (size_t)(k + 3) * H + c0);
#pragma unroll
    for (int r = 0; r < 8; ++r) {
      float4 a = *(const float4*)(xsrow + r * pitch + k);
      acc[r][0] += a.x * w0.x; acc[r][0] += a.y * w1.x; acc[r][0] += a.z * w2.x; acc[r][0] += a.w * w3.x;
      acc[r][1] += a.x * w0.y; acc[r][1] += a.y * w1.y; acc[r][1] += a.z * w2.y; acc[r][1] += a.w * w3.y;
      acc[r][2] += a.x * w0.z; acc[r][2] += a.y * w1.z; acc[r][2] += a.z * w2.z; acc[r][2] += a.w * w3.z;
      acc[r][3] += a.x * w0.w; acc[r][3] += a.y * w1.w; acc[r][3] += a.z * w2.w; acc[r][3] += a.w * w3.w;
    }
  }
}

// shared fp32 linear body: y[r0..r0+32) = x @ W  (K=128, N=128)
DEVFN void linear_body(const float* __restrict__ x, const float* __restrict__ W,
                       float* __restrict__ y, int r0, int R, int t, float* xs) {
  {
    const int r = t & 31, q = t >> 5;
    int row = r0 + r;
    if (row >= R) row = R - 1;
    const float* src = &x[(size_t)row * H + q * 32];
#pragma unroll
    for (int j = 0; j < 8; ++j)
      *(float4*)&xs[r * 132 + q * 32 + j * 4] = *(const float4*)&src[j * 4];
  }
  __syncthreads();
  const int c0 = (t & 31) * 4;
  const int rbase = (t >> 5) * 8;
  float acc[8][4];
#pragma unroll
  for (int r = 0; r < 8; ++r) { acc[r][0] = 0.f; acc[r][1] = 0.f; acc[r][2] = 0.f; acc[r][3] = 0.f; }
  mm_block(&xs[rbase * 132], 132, H, W, c0, acc);
#pragma unroll
  for (int r = 0; r < 8; ++r) {
    int row = r0 + rbase + r;
    if (row < R)
      *(float4*)&y[(size_t)row * H + c0] =
          make_float4(acc[r][0], acc[r][1], acc[r][2], acc[r][3]);
  }
}

// ---------------- fold stage 1: T = Wb@W0b (blocks 0-3), Wf = Wt@W0b (blocks 4-7) ----------------
__global__ __launch_bounds__(128) void fold1_kernel(
    const float* __restrict__ Wb, const float* __restrict__ Wt,
    const float* __restrict__ W0b, float* __restrict__ T,
    float* __restrict__ Wf) {
  __shared__ float xs[32 * 132];
  const float* x = (blockIdx.x < 4) ? Wb : Wt;
  float* y = (blockIdx.x < 4) ? T : Wf;
  linear_body(x, W0b, y, (blockIdx.x & 3) * 32, 128, threadIdx.x, xs);
}

// ---------------- fold stage 2: Wc2 = W1e@T (blocks 0-3), bc2 = b1e@T (block 4) ----------------
__global__ __launch_bounds__(128) void fold2_kernel(
    const float* __restrict__ W1e, const float* __restrict__ b1e,
    const float* __restrict__ T, float* __restrict__ Wc2,
    float* __restrict__ bc2) {
  __shared__ float xs[32 * 132];
  if (blockIdx.x < 4) {
    linear_body(W1e, T, Wc2, blockIdx.x * 32, 128, threadIdx.x, xs);
  } else {
    int j = threadIdx.x;
    float s = 0.f;
    for (int k = 0; k < H; ++k) s += b1e[k] * T[(size_t)k * H + j];
    bc2[j] = s;
  }
}

// ---------------- prepack 7 weight matrices -> MFMA B-fragment order, fp16 ----------------
__global__ __launch_bounds__(64) void prepack7_kernel(
    const float* __restrict__ s0, const float* __restrict__ s1,
    const float* __restrict__ s2, const float* __restrict__ s3,
    const float* __restrict__ s4, const float* __restrict__ s5,
    const float* __restrict__ s6, _Float16* __restrict__ pkBase) {
  const int z = blockIdx.z;
  const float* W = (z == 0) ? s0 : (z == 1) ? s1 : (z == 2) ? s2 :
                   (z == 3) ? s3 : (z == 4) ? s4 : (z == 5) ? s5 : s6;
  _Float16* pk = pkBase + (size_t)z * 128 * H;
  const int ks = blockIdx.x, ct = blockIdx.y, l = threadIdx.x;
  const int kbase = ks * 32 + (l >> 4) * 8;
  const int col = ct * 16 + (l & 15);
  _Float16 tmp[8];
#pragma unroll
  for (int j = 0; j < 8; ++j)
    tmp[j] = (_Float16)W[(size_t)(kbase + j) * H + col];
  *(f16x8*)&pk[((size_t)((ks * 8 + ct) * 64) + l) * 8] = *(f16x8*)tmp;
}

// ---- prepack W0e[16 x 128] -> MFMA B-fragment (K padded 16->32; row 16 = bias b0e) ----
__global__ __launch_bounds__(64) void prepack_w0e_kernel(
    const float* __restrict__ W0e, const float* __restrict__ b0e,
    _Float16* __restrict__ pk) {
  const int ct = blockIdx.x, l = threadIdx.x;
  const int quad = l >> 4;
  const int col = ct * 16 + (l & 15);
  _Float16 tmp[8];
#pragma unroll
  for (int j = 0; j < 8; ++j) {
    int k = quad * 8 + j;
    float v = (quad < 2) ? W0e[(size_t)k * H + col] : (k == 16 ? b0e[col] : 0.f);
    tmp[j] = (_Float16)v;
  }
  *(f16x8*)&pk[((size_t)(ct * 64) + l) * 8] = *(f16x8*)tmp;
}

// ---------------- prepack W[32 x 128] -> MFMA B-fragment (single K=32 step) ----------
__global__ __launch_bounds__(64) void prepack_k32_kernel(
    const float* __restrict__ W, _Float16* __restrict__ pk) {
  const int ct = blockIdx.x, l = threadIdx.x;
  const int quad = l >> 4;
  const int col = ct * 16 + (l & 15);
  _Float16 tmp[8];
#pragma unroll
  for (int j = 0; j < 8; ++j)
    tmp[j] = (_Float16)W[(size_t)(quad * 8 + j) * H + col];
  *(f16x8*)&pk[((size_t)(ct * 64) + l) * 8] = *(f16x8*)tmp;
}

// ---------------- counting sort by receiver ----------------
__global__ __launch_bounds__(256) void hist_kernel(const int* __restrict__ recv,
                                                   int* __restrict__ cnt) {
  int i = blockIdx.x * 256 + threadIdx.x;
  if (i < NE) atomicAdd(&cnt[recv[i]], 1);
}

__global__ __launch_bounds__(256) void scan1_kernel(const int* __restrict__ cnt,
                                                    int* __restrict__ excl,
                                                    int* __restrict__ part) {
  __shared__ int s[256];
  int t = threadIdx.x;
  int i = blockIdx.x * 256 + t;
  int v = (i < NN) ? cnt[i] : 0;
  s[t] = v;
  __syncthreads();
  for (int off = 1; off < 256; off <<= 1) {
    int x = (t >= off) ? s[t - off] : 0;
    __syncthreads();
    s[t] += x;
    __syncthreads();
  }
  if (i < NN) excl[i] = s[t] - v;
  if (t == 255) part[blockIdx.x] = s[255];
}

__global__ __launch_bounds__(256) void scan2_kernel(int* __restrict__ part, int nb) {
  __shared__ int s[256];
  int t = threadIdx.x;
  int v = (t < nb) ? part[t] : 0;
  s[t] = v;
  __syncthreads();
  for (int off = 1; off < 256; off <<= 1) {
    int x = (t >= off) ? s[t - off] : 0;
    __syncthreads();
    s[t] += x;
    __syncthreads();
  }
  if (t < nb) part[t] = s[t] - v;
}

__global__ __launch_bounds__(256) void scan3_kernel(int* __restrict__ excl,
                                                    const int* __restrict__ part,
                                                    int* __restrict__ cursor) {
  int i = blockIdx.x * 256 + threadIdx.x;
  if (i < NN) {
    int e = excl[i] + part[i >> 8];
    excl[i] = e;
    cursor[i] = e;
  }
}

// ---------------- scatter + edge-row permute (fp16) in ONE pass ----------------
__global__ __launch_bounds__(256) void scatter_permute_kernel(
    const int* __restrict__ senders, const int* __restrict__ recv,
    int* __restrict__ cursor, const float* __restrict__ edges,
    int* __restrict__ sendp, _Float16* __restrict__ edgesP16) {
  const int t = threadIdx.x;
  const int i = blockIdx.x * 64 + (t >> 2);
  if (i >= NE) return;
  const int sub = t & 3;
  int pos = 0;
  if (sub == 0) pos = atomicAdd(&cursor[recv[i]], 1);
  pos = __shfl(pos, (t & 63) & ~3);
  if (sub == 0) sendp[pos] = senders[i];
  float4 v = *(const float4*)&edges[(size_t)i * 16 + sub * 4];
  f16x4 h = {(_Float16)v.x, (_Float16)v.y, (_Float16)v.z, (_Float16)v.w};
  *(f16x4*)&edgesP16[(size_t)pos * 16 + sub * 4] = h;
}

// ---------------- MFMA encoder: n16 = relu(x@W0+b0)@W1+b1  (x is [NN,32] fp32) ----
__global__ __launch_bounds__(256) void encoder_mfma_kernel(
    const float* __restrict__ x, const float* __restrict__ b0,
    const float* __restrict__ b1, const _Float16* __restrict__ pkEW0,
    const _Float16* __restrict__ pkEW1, _Float16* __restrict__ outp) {
  __shared__ _Float16 lds[4][16 * 136];
  const int t = threadIdx.x;
  const int wave = t >> 6, lane = t & 63;
  const int row0 = blockIdx.x * 64 + wave * 16;
  const int quad = lane >> 4, m16 = lane & 15;
  _Float16* hlds = &lds[wave][0];

  int arow = row0 + m16;
  if (arow >= NN) arow = NN - 1;
  f16x8 a0;
  {
    const float* src = &x[(size_t)arow * 32 + quad * 8];
    float4 v0 = *(const float4*)(src);
    float4 v1 = *(const float4*)(src + 4);
    a0[0] = (_Float16)v0.x; a0[1] = (_Float16)v0.y;
    a0[2] = (_Float16)v0.z; a0[3] = (_Float16)v0.w;
    a0[4] = (_Float16)v1.x; a0[5] = (_Float16)v1.y;
    a0[6] = (_Float16)v1.z; a0[7] = (_Float16)v1.w;
  }
#pragma unroll
  for (int ct = 0; ct < 8; ++ct) {
    float bb = b0[ct * 16 + m16];
    f32x4 acc = (f32x4){bb, bb, bb, bb};
    acc = __builtin_amdgcn_mfma_f32_16x16x32_f16(
        a0, *(const f16x8*)&pkEW0[((size_t)(ct * 64) + lane) * 8], acc, 0, 0, 0);
#pragma unroll
    for (int q = 0; q < 4; ++q)
      hlds[(quad * 4 + q) * 136 + ct * 16 + m16] = (_Float16)fmaxf(acc[q], 0.f);
  }
  __syncthreads();
  const _Float16* hrow = &hlds[m16 * 136 + quad * 8];
  f16x8 ah[4];
#pragma unroll
  for (int ks = 0; ks < 4; ++ks) ah[ks] = *(const f16x8*)(hrow + ks * 32);
  f32x4 acc2[8];
#pragma unroll
  for (int ct = 0; ct < 8; ++ct) {
    float bb = b1[ct * 16 + m16];
    acc2[ct] = (f32x4){bb, bb, bb, bb};
  }
#pragma unroll
  for (int ks = 0; ks < 4; ++ks) {
    const _Float16* bp = pkEW1 + ((size_t)ks * 8 * 64 + lane) * 8;
#pragma unroll
    for (int ct = 0; ct < 8; ++ct)
      acc2[ct] = __builtin_amdgcn_mfma_f32_16x16x32_f16(
          ah[ks], *(const f16x8*)(bp + ct * 512), acc2[ct], 0, 0, 0);
  }
  __syncthreads();  // ah reads done before overwrite
#pragma unroll
  for (int ct = 0; ct < 8; ++ct)
#pragma unroll
    for (int q = 0; q < 4; ++q)
      hlds[(quad * 4 + q) * 136 + ct * 16 + m16] = (_Float16)acc2[ct][q];
  __syncthreads();
  {
    int lr = lane >> 2, cc = (lane & 3) * 32;
    int orow = row0 + lr;
    if (orow < NN) {
      const _Float16* src = &hlds[lr * 136 + cc];
      _Float16* dst = &outp[(size_t)orow * H + cc];
      *(f16x8*)(dst + 0)  = *(const f16x8*)(src + 0);
      *(f16x8*)(dst + 8)  = *(const f16x8*)(src + 8);
      *(f16x8*)(dst + 16) = *(const f16x8*)(src + 16);
      *(f16x8*)(dst + 24) = *(const f16x8*)(src + 24);
    }
  }
}

// ---------------- fused Hs + blin: B2pk = pack_C( Hs @ Wc2 + deg*bc2 + b0n ) ----------
// Block = one 16-node tile, 256 threads = 4 waves. Stage 1: wave w owns nodes
// tile*16 + w*4 + 0..3 — first edge-tile of all 4 nodes is PIPELINED, deg>16
// tails in a short residual loop. Bias folded into pkW0e row 16 via a
// constant-1 A column. Stage 2: one barrier, 4 waves x 2 ct-blocks of
// B2 = Hl@Wc2 + deg*bc2 + b0n (node_b0 folded here so node_mfma skips it).
__global__ __launch_bounds__(256) void hsblin_kernel(
    const _Float16* __restrict__ edgesP16, const int* __restrict__ start,
    const int* __restrict__ endc, const _Float16* __restrict__ pkW0e,
    const _Float16* __restrict__ pkWc2, const float* __restrict__ bc2,
    const float* __restrict__ b0n, _Float16* __restrict__ B2pk) {
  __shared__ _Float16 hl[16][136];
  __shared__ float degl[16];
  const int t = threadIdx.x;
  const int wave = t >> 6, lane = t & 63;
  const int quad = lane >> 4, m16 = lane & 15;
  const int tile = blockIdx.x;
  const int vb = tile * 16 + wave * 4;

  f16x8 bfrag[8];
#pragma unroll
  for (int ct = 0; ct < 8; ++ct)
    bfrag[ct] = *(const f16x8*)&pkW0e[((size_t)(ct * 64) + lane) * 8];

  int j0[4], dg[4];
#pragma unroll
  for (int k = 0; k < 4; ++k) j0[k] = start[vb + k];
#pragma unroll
  for (int k = 0; k < 4; ++k) dg[k] = endc[vb + k] - j0[k];

  float rs[4][8];
#pragma unroll
  for (int k = 0; k < 4; ++k)
#pragma unroll
    for (int ct = 0; ct < 8; ++ct) rs[k][ct] = 0.f;

  // ---- first edge-tile of all 4 nodes: loads issued back-to-back (ILP) ----
  f16x8 a0[4];
#pragma unroll
  for (int k = 0; k < 4; ++k) {
    const bool valid = (m16 < dg[k]);
    f16x8 a = {};
    if (quad < 2) {
      if (valid)
        a = *(const f16x8*)&edgesP16[(size_t)(j0[k] + m16) * 16 + quad * 8];
    } else if (quad == 2) {
      a[0] = valid ? (_Float16)1.f : (_Float16)0.f;
    }
    a0[k] = a;
  }
#pragma unroll
  for (int k = 0; k < 4; ++k) {
#pragma unroll
    for (int ct = 0; ct < 8; ++ct) {
      f32x4 acc = (f32x4){0.f, 0.f, 0.f, 0.f};
      acc = __builtin_amdgcn_mfma_f32_16x16x32_f16(a0[k], bfrag[ct], acc, 0, 0, 0);
      rs[k][ct] += (fmaxf(acc[0], 0.f) + fmaxf(acc[1], 0.f)) +
                   (fmaxf(acc[2], 0.f) + fmaxf(acc[3], 0.f));
    }
  }
  // ---- residual tiles for deg > 16 (rare) ----
#pragma unroll
  for (int k = 0; k < 4; ++k) {
    for (int base = 16; base < dg[k]; base += 16) {
      const bool valid = (base + m16 < dg[k]);
      f16x8 a = {};
      if (quad < 2) {
        if (valid)
          a = *(const f16x8*)&edgesP16[(size_t)(j0[k] + base + m16) * 16 + quad * 8];
      } else if (quad == 2) {
        a[0] = valid ? (_Float16)1.f : (_Float16)0.f;
      }
#pragma unroll
      for (int ct = 0; ct < 8; ++ct) {
        f32x4 acc = (f32x4){0.f, 0.f, 0.f, 0.f};
        acc = __builtin_amdgcn_mfma_f32_16x16x32_f16(a, bfrag[ct], acc, 0, 0, 0);
        rs[k][ct] += (fmaxf(acc[0], 0.f) + fmaxf(acc[1], 0.f)) +
                     (fmaxf(acc[2], 0.f) + fmaxf(acc[3], 0.f));
      }
    }
  }
  // ---- reduce 16 tile-rows per node; lanes 0..15 write the Hs row to LDS ----
#pragma unroll
  for (int k = 0; k < 4; ++k) {
#pragma unroll
    for (int ct = 0; ct < 8; ++ct) {
      float s = rs[k][ct];
      s += __shfl_xor(s, 16);
      s += __shfl_xor(s, 32);
      rs[k][ct] = s;
    }
    const int nl = wave * 4 + k;
    if (lane < 16) {
#pragma unroll
      for (int ct = 0; ct < 8; ++ct)
        hl[nl][ct * 16 + lane] = (_Float16)rs[k][ct];
    }
    if (lane == 16) degl[nl] = (float)dg[k];
  }
  __syncthreads();

  // ---- stage 2: wave handles ct = 2*wave, 2*wave+1 ----
  f16x8 ah[4];
#pragma unroll
  for (int ks = 0; ks < 4; ++ks)
    ah[ks] = *(const f16x8*)&hl[m16][ks * 32 + quad * 8];
  float degq[4];
#pragma unroll
  for (int q = 0; q < 4; ++q) degq[q] = degl[quad * 4 + q];
  f32x4 acc2[2];
#pragma unroll
  for (int i = 0; i < 2; ++i) {
    int ct = wave * 2 + i;
    float bcv = bc2[ct * 16 + m16];
    float b0v = b0n[ct * 16 + m16];
    acc2[i] = (f32x4){degq[0] * bcv + b0v, degq[1] * bcv + b0v,
                      degq[2] * bcv + b0v, degq[3] * bcv + b0v};
  }
#pragma unroll
  for (int ks = 0; ks < 4; ++ks) {
#pragma unroll
    for (int i = 0; i < 2; ++i) {
      int ct = wave * 2 + i;
      const _Float16* bp = pkWc2 + ((size_t)((ks * 8 + ct) * 64) + lane) * 8;
      acc2[i] = __builtin_amdgcn_mfma_f32_16x16x32_f16(
          ah[ks], *(const f16x8*)bp, acc2[i], 0, 0, 0);
    }
  }
  _Float16 tmp[8];
#pragma unroll
  for (int i = 0; i < 2; ++i)
#pragma unroll
    for (int q = 0; q < 4; ++q) tmp[i * 4 + q] = (_Float16)acc2[i][q];
  *(f16x8*)&B2pk[((size_t)tile * 64 + lane) * 32 + wave * 8] = *(f16x8*)tmp;
}

// ---------------- per-pass: S[v] = sum_{s in N(v)} n16[s]  (16-deep ILP) ----------
__global__ __launch_bounds__(256) void gather_kernel(
    const _Float16* __restrict__ n16, const int* __restrict__ start,
    const int* __restrict__ endc, const int* __restrict__ sendp,
    _Float16* __restrict__ S) {
  const int t = threadIdx.x;
  const int v = blockIdx.x * 4 + (t >> 6);  // NN % 4 == 0
  const int lane = t & 63;
  const int grp = lane >> 4;
  const int c = (lane & 15) * 8;
  float a[8] = {0.f, 0.f, 0.f, 0.f, 0.f, 0.f, 0.f, 0.f};
  const int e = endc[v];
  for (int j = start[v]; j < e; j += 16) {
    int js[4];
    float w[4];
#pragma unroll
    for (int i = 0; i < 4; ++i) {
      int jj = j + grp + i * 4;
      w[i] = (jj < e) ? 1.f : 0.f;
      js[i] = (jj < e) ? jj : (e - 1);
    }
    int sx[4];
#pragma unroll
    for (int i = 0; i < 4; ++i) sx[i] = sendp[js[i]];
    f16x8 p[4];
#pragma unroll
    for (int i = 0; i < 4; ++i)
      p[i] = *(const f16x8*)&n16[(size_t)sx[i] * H + c];
#pragma unroll
    for (int i = 0; i < 4; ++i)
#pragma unroll
      for (int k = 0; k < 8; ++k) a[k] = fmaf(w[i], (float)p[i][k], a[k]);
  }
#pragma unroll
  for (int i = 0; i < 8; ++i) {
    a[i] += __shfl_xor(a[i], 16);
    a[i] += __shfl_xor(a[i], 32);
  }
  if (lane < 16) {
    f16x8 o;
#pragma unroll
    for (int i = 0; i < 8; ++i) o[i] = (_Float16)a[i];
    *(f16x8*)&S[(size_t)v * H + c] = o;
  }
}

// ---------------- MFMA node update (v2: 32 rows per wave, 2x B-fragment reuse) ----
// pre-act = n@W0t + S@Wf + B2' ; h = relu(pre-act)   (B2' has b0 pre-folded)
// out = LN(h@W1 + n@Wn + b1)
// Each wave owns TWO 16-row tiles; every B-fragment load feeds 2 MFMAs per
// stream (4 with the n/S pair). LDS h-buffers are per-wave => no barriers.
__global__ __launch_bounds__(256) void node_mfma_kernel(
    const _Float16* __restrict__ n16, const _Float16* __restrict__ S16,
    const _Float16* __restrict__ B2pk,
    const _Float16* __restrict__ pkW0t, const _Float16* __restrict__ pkWf,
    const _Float16* __restrict__ pkW1, const _Float16* __restrict__ pkWn,
    const float* __restrict__ b1,
    const float* __restrict__ ln_g, const float* __restrict__ ln_b,
    _Float16* __restrict__ nout) {
  __shared__ _Float16 lds[4][2][16 * 136];
  const int t = threadIdx.x;
  const int wave = t >> 6, lane = t & 63;
  const int row0 = blockIdx.x * 128 + wave * 32;
  const int quad = lane >> 4, m16 = lane & 15;

  int ar0 = row0 + m16;       if (ar0 >= NN) ar0 = NN - 1;
  int ar1 = row0 + 16 + m16;  if (ar1 >= NN) ar1 = NN - 1;
  const _Float16* nr0 = &n16[(size_t)ar0 * H + quad * 8];
  const _Float16* nr1 = &n16[(size_t)ar1 * H + quad * 8];
  const _Float16* sr0 = &S16[(size_t)ar0 * H + quad * 8];
  const _Float16* sr1 = &S16[(size_t)ar1 * H + quad * 8];

  // resident n fragments (used in both phases)
  f16x8 an0[4], an1[4];
#pragma unroll
  for (int ks = 0; ks < 4; ++ks) {
    an0[ks] = *(const f16x8*)(nr0 + ks * 32);
    an1[ks] = *(const f16x8*)(nr1 + ks * 32);
  }

  const int tile0 = blockIdx.x * 8 + wave * 2;
  const _Float16* b2l0 = &B2pk[((size_t)tile0 * 64 + lane) * 32];
  const _Float16* b2l1 = &B2pk[((size_t)(tile0 + 1) * 64 + lane) * 32];
  f32x4 acc0[8], acc1[8];
#pragma unroll
  for (int ct = 0; ct < 8; ++ct) {
    f16x4 v0 = *(const f16x4*)(b2l0 + ct * 4);
    f16x4 v1 = *(const f16x4*)(b2l1 + ct * 4);
    acc0[ct] = (f32x4){(float)v0[0], (float)v0[1], (float)v0[2], (float)v0[3]};
    acc1[ct] = (f32x4){(float)v1[0], (float)v1[1], (float)v1[2], (float)v1[3]};
  }
  // ---- phase 1: pre-act = n@W0t + S@Wf + B2' ----
#pragma unroll
  for (int ks = 0; ks < 4; ++ks) {
    f16x8 as0 = *(const f16x8*)(sr0 + ks * 32);
    f16x8 as1 = *(const f16x8*)(sr1 + ks * 32);
    const _Float16* bp0 = pkW0t + ((size_t)ks * 8 * 64 + lane) * 8;
    const _Float16* bpf = pkWf + ((size_t)ks * 8 * 64 + lane) * 8;
#pragma unroll
    for (int ct = 0; ct < 8; ++ct) {
      f16x8 bw0 = *(const f16x8*)(bp0 + ct * 512);
      acc0[ct] = __builtin_amdgcn_mfma_f32_16x16x32_f16(an0[ks], bw0, acc0[ct], 0, 0, 0);
      acc1[ct] = __builtin_amdgcn_mfma_f32_16x16x32_f16(an1[ks], bw0, acc1[ct], 0, 0, 0);
      f16x8 bwf = *(const f16x8*)(bpf + ct * 512);
      acc0[ct] = __builtin_amdgcn_mfma_f32_16x16x32_f16(as0, bwf, acc0[ct], 0, 0, 0);
      acc1[ct] = __builtin_amdgcn_mfma_f32_16x16x32_f16(as1, bwf, acc1[ct], 0, 0, 0);
    }
  }
  // relu -> per-wave LDS (same-wave RAW; compiler orders via lgkmcnt)
  _Float16* h0 = &lds[wave][0][0];
  _Float16* h1 = &lds[wave][1][0];
#pragma unroll
  for (int ct = 0; ct < 8; ++ct) {
#pragma unroll
    for (int q = 0; q < 4; ++q) {
      h0[(quad * 4 + q) * 136 + ct * 16 + m16] = (_Float16)fmaxf(acc0[ct][q], 0.f);
      h1[(quad * 4 + q) * 136 + ct * 16 + m16] = (_Float16)fmaxf(acc1[ct][q], 0.f);
    }
  }
  // ---- phase 2: out = h@W1 + n@Wn + b1 ----
#pragma unroll
  for (int ct = 0; ct < 8; ++ct) {
    float bb = b1[ct * 16 + m16];
    acc0[ct] = (f32x4){bb, bb, bb, bb};
    acc1[ct] = (f32x4){bb, bb, bb, bb};
  }
  const _Float16* hr0 = &lds[wave][0][m16 * 136 + quad * 8];
  const _Float16* hr1 = &lds[wave][1][m16 * 136 + quad * 8];
#pragma unroll
  for (int ks = 0; ks < 4; ++ks) {
    f16x8 ah0 = *(const f16x8*)(hr0 + ks * 32);
    f16x8 ah1 = *(const f16x8*)(hr1 + ks * 32);
    const _Float16* bp1 = pkW1 + ((size_t)ks * 8 * 64 + lane) * 8;
    const _Float16* bpn = pkWn + ((size_t)ks * 8 * 64 + lane) * 8;
#pragma unroll
    for (int ct = 0; ct < 8; ++ct) {
      f16x8 b1f = *(const f16x8*)(bp1 + ct * 512);
      acc0[ct] = __builtin_amdgcn_mfma_f32_16x16x32_f16(ah0, b1f, acc0[ct], 0, 0, 0);
      acc1[ct] = __builtin_amdgcn_mfma_f32_16x16x32_f16(ah1, b1f, acc1[ct], 0, 0, 0);
      f16x8 bnf = *(const f16x8*)(bpn + ct * 512);
      acc0[ct] = __builtin_amdgcn_mfma_f32_16x16x32_f16(an0[ks], bnf, acc0[ct], 0, 0, 0);
      acc1[ct] = __builtin_amdgcn_mfma_f32_16x16x32_f16(an1[ks], bnf, acc1[ct], 0, 0, 0);
    }
  }

  float gv[8], bv[8];
#pragma unroll
  for (int ct = 0; ct < 8; ++ct) {
    gv[ct] = ln_g[ct * 16 + m16];
    bv[ct] = ln_b[ct * 16 + m16];
  }
  // ---- LayerNorm + store, per tile (wave owns full rows: in-wave shfl) ----
#pragma unroll
  for (int q = 0; q < 4; ++q) {
    float s1 = 0.f, s2 = 0.f;
#pragma unroll
    for (int ct = 0; ct < 8; ++ct) {
      float v = acc0[ct][q];
      s1 += v; s2 += v * v;
    }
#pragma unroll
    for (int m = 1; m <= 8; m <<= 1) {
      s1 += __shfl_xor(s1, m);
      s2 += __shfl_xor(s2, m);
    }
    float mu = s1 * (1.f / 128.f);
    float var = s2 * (1.f / 128.f) - mu * mu;
    float rs = rsqrtf(var + LN_EPS);
#pragma unroll
    for (int ct = 0; ct < 8; ++ct) {
      float o = (acc0[ct][q] - mu) * rs * gv[ct] + bv[ct];
      h0[(quad * 4 + q) * 136 + ct * 16 + m16] = (_Float16)o;
    }
  }
#pragma unroll
  for (int q = 0; q < 4; ++q) {
    float s1 = 0.f, s2 = 0.f;
#pragma unroll
    for (int ct = 0; ct < 8; ++ct) {
      float v = acc1[ct][q];
      s1 += v; s2 += v * v;
    }
#pragma unroll
    for (int m = 1; m <= 8; m <<= 1) {
      s1 += __shfl_xor(s1, m);
      s2 += __shfl_xor(s2, m);
    }
    float mu = s1 * (1.f / 128.f);
    float var = s2 * (1.f / 128.f) - mu * mu;
    float rs = rsqrtf(var + LN_EPS);
#pragma unroll
    for (int ct = 0; ct < 8; ++ct) {
      float o = (acc1[ct][q] - mu) * rs * gv[ct] + bv[ct];
      h1[(quad * 4 + q) * 136 + ct * 16 + m16] = (_Float16)o;
    }
  }
  {
    int lr = lane >> 2;
    int cc = (lane & 3) * 32;
    const _Float16* src0 = &lds[wave][0][lr * 136 + cc];
    int orow0 = row0 + lr;
    if (orow0 < NN) {
      _Float16* dst = &nout[(size_t)orow0 * H + cc];
      *(f16x8*)(dst + 0)  = *(const f16x8*)(src0 + 0);
      *(f16x8*)(dst + 8)  = *(const f16x8*)(src0 + 8);
      *(f16x8*)(dst + 16) = *(const f16x8*)(src0 + 16);
      *(f16x8*)(dst + 24) = *(const f16x8*)(src0 + 24);
    }
    const _Float16* src1 = &lds[wave][1][lr * 136 + cc];
    int orow1 = row0 + 16 + lr;
    if (orow1 < NN) {
      _Float16* dst = &nout[(size_t)orow1 * H + cc];
      *(f16x8*)(dst + 0)  = *(const f16x8*)(src1 + 0);
      *(f16x8*)(dst + 8)  = *(const f16x8*)(src1 + 8);
      *(f16x8*)(dst + 16) = *(const f16x8*)(src1 + 16);
      *(f16x8*)(dst + 24) = *(const f16x8*)(src1 + 24);
    }
  }
}

// ---------------- MFMA decoder: out = relu(n@W0+b0)@W1 + b1  (layer2 fp32) ----------
__global__ __launch_bounds__(256) void decode_mfma_kernel(
    const _Float16* __restrict__ n, const float* __restrict__ b0,
    const _Float16* __restrict__ pkDW0, const float* __restrict__ W1,
    const float* __restrict__ b1, float* __restrict__ out) {
  const int t = threadIdx.x;
  const int wave = t >> 6, lane = t & 63;
  const int row0 = blockIdx.x * 64 + wave * 16;
  const int quad = lane >> 4, m16 = lane & 15;
  int arow = row0 + m16;
  if (arow >= NN) arow = NN - 1;
  const _Float16* nrow = &n[(size_t)arow * H + quad * 8];
  f16x8 an[4];
#pragma unroll
  for (int ks = 0; ks < 4; ++ks) an[ks] = *(const f16x8*)(nrow + ks * 32);
  f32x4 acc[8];
#pragma unroll
  for (int ct = 0; ct < 8; ++ct) {
    float bb = b0[ct * 16 + m16];
    acc[ct] = (f32x4){bb, bb, bb, bb};
  }
#pragma unroll
  for (int ks = 0; ks < 4; ++ks) {
    const _Float16* bp = pkDW0 + ((size_t)ks * 8 * 64 + lane) * 8;
#pragma unroll
    for (int ct = 0; ct < 8; ++ct)
      acc[ct] = __builtin_amdgcn_mfma_f32_16x16x32_f16(
          an[ks], *(const f16x8*)(bp + ct * 512), acc[ct], 0, 0, 0);
  }
  float s0[4] = {0.f, 0.f, 0.f, 0.f}, s1[4] = {0.f, 0.f, 0.f, 0.f};
#pragma unroll
  for (int ct = 0; ct < 8; ++ct) {
    const float2 w = *(const float2*)&W1[(size_t)(ct * 16 + m16) * 2];
#pragma unroll
    for (int q = 0; q < 4; ++q) {
      float h = fmaxf(acc[ct][q], 0.f);
      s0[q] += h * w.x;
      s1[q] += h * w.y;
    }
  }
#pragma unroll
  for (int q = 0; q < 4; ++q) {
#pragma unroll
    for (int m = 1; m <= 8; m <<= 1) {
      s0[q] += __shfl_xor(s0[q], m);
      s1[q] += __shfl_xor(s1[q], m);
    }
  }
  if (m16 == 0) {
#pragma unroll
    for (int q = 0; q < 4; ++q) {
      int r = row0 + quad * 4 + q;
      if (r < NN) {
        out[(size_t)r * 2 + 0] = s0[q] + b1[0];
        out[(size_t)r * 2 + 1] = s1[q] + b1[1];
      }
    }
  }
}

__global__ __launch_bounds__(256) void zero_kernel(float4* __restrict__ p, int n4) {
  int i = blockIdx.x * 256 + threadIdx.x;
  if (i < n4) p[i] = make_float4(0.f, 0.f, 0.f, 0.f);
}

}  // namespace

extern "C" void kernel_launch(void* const* d_in, const int* in_sizes, int n_in,
                              void* d_out, int out_size, void* d_ws, size_t ws_size,
                              hipStream_t stream) {
  const float* nodes     = (const float*)d_in[0];
  const float* edges     = (const float*)d_in[1];
  const int*   senders   = (const int*)d_in[2];
  const int*   receivers = (const int*)d_in[3];
  const float* enc_n_W0 = (const float*)d_in[4];
  const float* enc_n_b0 = (const float*)d_in[5];
  const float* enc_n_W1 = (const float*)d_in[6];
  const float* enc_n_b1 = (const float*)d_in[7];
  const float* enc_e_W0 = (const float*)d_in[8];
  const float* enc_e_b0 = (const float*)d_in[9];
  const float* enc_e_W1 = (const float*)d_in[10];
  const float* enc_e_b1 = (const float*)d_in[11];
  const float* W_msg    = (const float*)d_in[12];
  const float* node_W0  = (const float*)d_in[13];
  const float* node_b0  = (const float*)d_in[14];
  const float* node_W1  = (const float*)d_in[15];
  const float* node_b1  = (const float*)d_in[16];
  const float* W_node   = (const float*)d_in[17];
  const float* ln_g     = (const float*)d_in[18];
  const float* ln_b     = (const float*)d_in[19];
  const float* dec_W0   = (const float*)d_in[20];
  const float* dec_b0   = (const float*)d_in[21];
  const float* dec_W1   = (const float*)d_in[22];
  const float* dec_b1   = (const float*)d_in[23];
  float* out = (float*)d_out;

  const float* Wt  = W_msg;                // rows 0..127 of W_msg
  const float* Wb  = W_msg + 128 * H;      // rows 128..255
  const float* W0t = node_W0;              // rows 0..127 of node_W0
  const float* W0b = node_W0 + 128 * H;    // rows 128..255

  const int mfmaBlocks = (NN + 63) / 64;   // 782 (encoder/decoder)
  const int nodeBlocks128 = (NN + 127) / 128;  // 391 (node update v2)
  const int nTiles     = mfmaBlocks * 4;   // 3128 (= nodeBlocks128*8)
  const int hsTiles    = NN / 16;          // 3125 (exact)

  // workspace layout
  float* T      = (float*)d_ws;                        // 128*128 f32
  float* Wc2    = T + 128 * H;
  float* Wf32   = Wc2 + 128 * H;
  float* bc2    = Wf32 + 128 * H;                      // 128
  _Float16* edgesP16 = (_Float16*)(bc2 + 128);         // NE*16 f16 (19.2 MB)
  _Float16* n16a  = edgesP16 + (size_t)NE * 16;        // NN*H f16
  _Float16* n16b  = n16a + (size_t)NN * H;
  _Float16* S16   = n16b + (size_t)NN * H;
  _Float16* B2pk  = S16 + (size_t)NN * H;              // nTiles*64*32 f16
  _Float16* pkAll = B2pk + (size_t)nTiles * 64 * 32;   // 7 x 128*H f16 contiguous
  _Float16* pkW0t = pkAll;
  _Float16* pkWf  = pkAll + 1 * 128 * H;
  _Float16* pkW1  = pkAll + 2 * 128 * H;
  _Float16* pkWn  = pkAll + 3 * 128 * H;
  _Float16* pkEW1 = pkAll + 4 * 128 * H;
  _Float16* pkDW0 = pkAll + 5 * 128 * H;
  _Float16* pkWc2 = pkAll + 6 * 128 * H;
  _Float16* pkW0e = pkAll + 7 * 128 * H;               // 8*64*8 = 4096 f16
  _Float16* pkEW0 = pkW0e + 4096;                      // 4096 f16
  int* cnt    = (int*)(pkEW0 + 4096);
  int* excl   = cnt + NN;
  int* cursor = excl + NN;
  int* part   = cursor + NN;               // 256
  int* sendp  = part + 256;                // NE

  const int scanBlocks = (NN + 255) / 256;   // 196
  const int neBlocks   = (NE + 255) / 256;   // 2344

  // --- one-time: sort edges by receiver (scatter fused with fp16 row permute) ---
  zero_kernel<<<(NN / 4 + 255) / 256, 256, 0, stream>>>((float4*)cnt, NN / 4);
  hist_kernel<<<neBlocks, 256, 0, stream>>>(receivers, cnt);
  scan1_kernel<<<scanBlocks, 256, 0, stream>>>(cnt, excl, part);
  scan2_kernel<<<1, 256, 0, stream>>>(part, scanBlocks);
  scan3_kernel<<<scanBlocks, 256, 0, stream>>>(excl, part, cursor);
  scatter_permute_kernel<<<(NE + 63) / 64, 256, 0, stream>>>(
      senders, receivers, cursor, edges, sendp, edgesP16);

  // --- fold chains:  T = Wb@W0b; Wf = Wt@W0b;  then Wc2 = W1e@T, bc2 = b1e@T ---
  fold1_kernel<<<8, 128, 0, stream>>>(Wb, Wt, W0b, T, Wf32);
  fold2_kernel<<<5, 128, 0, stream>>>(enc_e_W1, enc_e_b1, T, Wc2, bc2);
  prepack7_kernel<<<dim3(4, 8, 7), 64, 0, stream>>>(
      W0t, Wf32, node_W1, W_node, enc_n_W1, dec_W0, Wc2, pkAll);
  prepack_w0e_kernel<<<8, 64, 0, stream>>>(enc_e_W0, enc_e_b0, pkW0e);
  prepack_k32_kernel<<<8, 64, 0, stream>>>(enc_n_W0, pkEW0);

  encoder_mfma_kernel<<<mfmaBlocks, 256, 0, stream>>>(
      nodes, enc_n_b0, enc_n_b1, pkEW0, pkEW1, n16a);
  // zero the 3 tail tiles of B2pk (read by node_mfma's dead rows; NaN-proofing)
  zero_kernel<<<3, 256, 0, stream>>>(
      (float4*)(B2pk + (size_t)hsTiles * 64 * 32), (nTiles - hsTiles) * 512);
  hsblin_kernel<<<hsTiles, 256, 0, stream>>>(
      edgesP16, excl, cursor, pkW0e, pkWc2, bc2, node_b0, B2pk);

  // --- 5 weight-tied passes ---
  _Float16* ncur = n16a;
  _Float16* nnxt = n16b;
  for (int p = 0; p < 5; ++p) {
    gather_kernel<<<NN / 4, 256, 0, stream>>>(ncur, excl, cursor, sendp, S16);
    node_mfma_kernel<<<nodeBlocks128, 256, 0, stream>>>(
        ncur, S16, B2pk, pkW0t, pkWf, pkW1, pkWn, node_b1,
        ln_g, ln_b, nnxt);
    _Float16* tmp = ncur; ncur = nnxt; nnxt = tmp;
  }

  decode_mfma_kernel<<<mfmaBlocks, 256, 0, stream>>>(
      ncur, dec_b0, pkDW0, dec_W1, dec_b1, out);
}